// Round 4
// baseline (660.062 us; speedup 1.0000x reference)
//
#include <hip/hip_runtime.h>

// CRF NLL: B=256 batches, S=2048 steps, T=64 tags.
// Single kernel: one wave per batch (lane = tag). Exp-space forward recurrence,
// exact power-of-2 renorm, q broadcast via LDS f16 round-trip (wave-synchronous,
// no barrier), 64-term MAC via v_pk_fma_f16. Numerator (gold-path score) fused
// into lanes 0-7's latency shadow.
#define BB 256
#define SS 2048
#define TT 64

typedef __fp16 half2v __attribute__((ext_vector_type(2)));
typedef __fp16 half8v __attribute__((ext_vector_type(8)));

__device__ __forceinline__ float rfl_f(float x) {
  return __builtin_bit_cast(float, __builtin_amdgcn_readfirstlane(__builtin_bit_cast(int, x)));
}

// Invariant: alpha_j = ln2 * (log2(q_j) + gamma), q_0 in [2^-6, 2^-5).
// E2[i] = (exp(trans[2i][j]), exp(trans[2i+1][j])) * 2^-5 (f16 pair, lane's j).
// gamma tracked as: gamma_init + esum - 116*nsteps (exact ints).
// qsh holds current q as f16; each step reads all 64 (broadcast b128) and
// writes the renormalized successor for lane j.
__device__ __forceinline__ void crf_step(float& q, int& esum, float x,
                                         const half2v (&E2)[32],
                                         __fp16* qsh, int j) {
  const half8v* qv = (const half8v*)qsh;
  half2v a0 = (half2v)0, a1 = (half2v)0, a2 = (half2v)0, a3 = (half2v)0;
#pragma unroll
  for (int m = 0; m < 8; ++m) {
    half8v blk = qv[m];  // q[8m..8m+7], one ds_read_b128 (broadcast)
    a0 += __builtin_shufflevector(blk, blk, 0, 1) * E2[4 * m + 0];
    a1 += __builtin_shufflevector(blk, blk, 2, 3) * E2[4 * m + 1];
    a2 += __builtin_shufflevector(blk, blk, 4, 5) * E2[4 * m + 2];
    a3 += __builtin_shufflevector(blk, blk, 6, 7) * E2[4 * m + 3];
  }
  half2v s = (a0 + a1) + (a2 + a3);
  float y = (float)s[0] + (float)s[1];
  float t = y * x;                      // > 0 always
  float v = rfl_f(t);                   // lane-0 value, uniform
  int eb = __builtin_bit_cast(int, v) & 0x7f800000;
  float scale = __builtin_bit_cast(float, 0x7C000000 - eb);  // 2^(121-e), exact
  q = t * scale;                        // q_0 back in [2^-6, 2^-5)
  esum += (eb >> 23);                   // exact integer exponent bookkeeping
  qsh[j] = (__fp16)q;                   // publish for next step (ds_write_b16)
}

__device__ __forceinline__ void prefetch8(float (&buf)[8], int& mreg, float& tvg,
                                          float& evg, int i0,
                                          const float* __restrict__ ep,
                                          const float* __restrict__ emb,
                                          const int* __restrict__ mp,
                                          const int* __restrict__ tg,
                                          const float* __restrict__ trans, int j) {
#pragma unroll
  for (int t = 0; t < 8; ++t) {
    int ii = i0 + t;
    ii = ii > SS - 1 ? SS - 1 : ii;     // clamp: harmless dup load
    buf[t] = ep[ii * TT];
  }
  int mi = i0 + (j & 7);
  int mc = mi > SS - 1 ? SS - 1 : mi;
  mreg = (mi > SS - 1) ? 0 : mp[mc];    // OOB steps masked off
  tvg = 0.f;
  evg = 0.f;
  if (j < 8) {                          // numerator gathers for this block's 8 steps
    int tgc = tg[mc];
    int tgp = tg[mc - 1];               // mc >= 1 always (i0 >= 1)
    tvg = trans[tgp * TT + tgc];
    evg = emb[(size_t)mc * TT + tgc];
  }
}

__device__ __forceinline__ void process8(float& q, int& esum, int& nsteps,
                                         const float (&buf)[8], int mreg,
                                         const half2v (&E2)[32], __fp16* qsh, int j) {
  unsigned long long bal = __ballot(mreg != 0);
  if (bal == ~0ull) {                   // fast path: all 8 steps active
    float xs[8];
#pragma unroll
    for (int t = 0; t < 8; ++t) xs[t] = __expf(buf[t]);
#pragma unroll
    for (int t = 0; t < 8; ++t) crf_step(q, esum, xs[t], E2, qsh, j);
    nsteps += 8;
  } else {                              // rare: per-step uniform branch
#pragma unroll
    for (int t = 0; t < 8; ++t) {
      int mv = __builtin_amdgcn_readlane(mreg, t);
      if (mv) {
        crf_step(q, esum, __expf(buf[t]), E2, qsh, j);
        nsteps += 1;
      }
    }
  }
}

__global__ __launch_bounds__(64, 1) void crf_kernel(
    const float* __restrict__ em, const float* __restrict__ startT,
    const float* __restrict__ endT, const float* __restrict__ trans,
    const int* __restrict__ tags, const int* __restrict__ mask,
    float* __restrict__ out) {
  __shared__ alignas(16) __fp16 qsh[TT];
  const int b = blockIdx.x;
  const int j = threadIdx.x;            // tag index, one wave per batch

  half2v E2[32];
#pragma unroll
  for (int m = 0; m < 32; ++m) {
    float e0 = __expf(trans[(2 * m) * TT + j]) * 0.03125f;
    float e1 = __expf(trans[(2 * m + 1) * TT + j]) * 0.03125f;
    E2[m] = __builtin_amdgcn_cvt_pkrtz(e0, e1);
  }

  const float* emb = em + (size_t)b * SS * TT;
  const float* ep = emb + j;
  const int* mp = mask + b * SS;
  const int* tg = tags + b * SS;

  // init: alpha0 = start + em[0]; q = exp(alpha0 - alpha0[0]) * 2^-6
  float a0v = startT[j] + ep[0];
  float a00 = rfl_f(a0v);
  float q = __expf(a0v - a00) * 0.015625f;
  float gamma0 = a00 * 1.4426950408889634f + 6.0f;
  int esum = 0, nsteps = 0;
  qsh[j] = (__fp16)q;

  // numerator partial: step-0 term on lane 0
  int tg0 = tg[0];
  float pnum = 0.f;
  if (j == 0) pnum = startT[tg0] + emb[tg0];

  // steps i = 1..2047 as 256 chunks of 8 (chunk 255 pads step 2048, masked off)
  float bufA[8], bufB[8];
  int mA, mB;
  float tvA, evA, tvB, evB;
  prefetch8(bufA, mA, tvA, evA, 1, ep, emb, mp, tg, trans, j);
  for (int c = 0; c < 256; c += 2) {
    prefetch8(bufB, mB, tvB, evB, 1 + 8 * (c + 1), ep, emb, mp, tg, trans, j);
    process8(q, esum, nsteps, bufA, mA, E2, qsh, j);
    pnum += (mA != 0) ? (tvA + evA) : 0.f;   // lanes >=8 carry zeros
    prefetch8(bufA, mA, tvA, evA, 1 + 8 * (c + 2), ep, emb, mp, tg, trans, j);
    process8(q, esum, nsteps, bufB, mB, E2, qsh, j);
    pnum += (mB != 0) ? (tvB + evB) : 0.f;
  }

  // denominator = logsumexp_j(alpha_j + end_j)
  float gamma = gamma0 + (float)esum - 116.0f * (float)nsteps;
  float alpha = (__log2f(q) + gamma) * 0.69314718055994531f;
  float tj = alpha + endT[j];
  float mx = tj;
#pragma unroll
  for (int o = 32; o > 0; o >>= 1) mx = fmaxf(mx, __shfl_xor(mx, o, 64));
  float ex = __expf(tj - mx);
#pragma unroll
  for (int o = 32; o > 0; o >>= 1) ex += __shfl_xor(ex, o, 64);
  float den = mx + __logf(ex);

  // numerator total: sum lanes' partials (only 0-7 nonzero)
  float nsum = pnum;
#pragma unroll
  for (int o = 32; o > 0; o >>= 1) nsum += __shfl_xor(nsum, o, 64);

  if (j == 0) {
    int lastTag = tg[nsteps];           // seq_len-1 == nsteps
    float nm = nsum + endT[lastTag];
    atomicAdd(out, (den - nm) * (1.0f / BB));
  }
}

extern "C" void kernel_launch(void* const* d_in, const int* in_sizes, int n_in,
                              void* d_out, int out_size, void* d_ws, size_t ws_size,
                              hipStream_t stream) {
  const float* em = (const float*)d_in[0];
  const float* startT = (const float*)d_in[1];
  const float* endT = (const float*)d_in[2];
  const float* trans = (const float*)d_in[3];
  const int* tags = (const int*)d_in[4];
  const int* mask = (const int*)d_in[5];
  float* out = (float*)d_out;

  (void)hipMemsetAsync(out, 0, sizeof(float), stream);
  crf_kernel<<<BB, 64, 0, stream>>>(em, startT, endT, trans, tags, mask, out);
}